// Round 5
// baseline (4807.271 us; speedup 1.0000x reference)
//
#include <hip/hip_runtime.h>
#include <cstdint>
#include <cstddef>

// BottomUpNet: N=8192 rows independent; K=16 sequential steps.
// m-chain (summary recurrence): fp16 hi/lo split, 3 MFMAs => ~fp32 exact.
// h-chain (h1,h2 -> pred): plain fp16, 1 MFMA (non-compounding).
// R5: 128x64 tiles -> 1024-block grids (4 blocks/CU co-resident) to hide the
// global_load_lds barrier drain (R4 was stall-bound at 2 blocks/CU: MfmaUtil
// 30 / VALU 11 / HBM 14 with all throughput floors << measured time).

typedef _Float16 f16x8 __attribute__((ext_vector_type(8)));
typedef float f32x16 __attribute__((ext_vector_type(16)));

__device__ __forceinline__ void gload16(const void* g, void* l) {
  // async global->LDS, 16B/lane, LDS dest = wave-uniform base + lane*16
  __builtin_amdgcn_global_load_lds(
      (__attribute__((address_space(1))) void*)const_cast<void*>(g),
      (__attribute__((address_space(3))) void*)l,
      16, 0, 0);
}

// ---- split GEMM: C = relu(A@B^T + bias), A,B,C hi/lo fp16 (3 MFMAs => ~fp32)
// Tile 128x64, BK=32, 256 thr; wave grid 2x2, wave tile 64x32 = 2x1 of 32x32.
__global__ __launch_bounds__(256, 4)
void gemm_split_kernel(const _Float16* __restrict__ AH0, const _Float16* __restrict__ AL0, int ldA0,
                       const _Float16* __restrict__ AH1, const _Float16* __restrict__ AL1, int ldA1,
                       int kcut, int Ktot,
                       const _Float16* __restrict__ BH, const _Float16* __restrict__ BL,
                       const float* __restrict__ bias,
                       _Float16* __restrict__ CH, _Float16* __restrict__ CL, int ldC)
{
  __shared__ _Float16 sAh[128 * 32];
  __shared__ _Float16 sAl[128 * 32];
  __shared__ _Float16 sBh[64 * 32];
  __shared__ _Float16 sBl[64 * 32];

  const int lane = threadIdx.x & 63;
  const int wave = threadIdx.x >> 6;
  const int wm = (wave >> 1) * 64, wn = (wave & 1) * 32;
  const int mBase = blockIdx.x * 128, nBase = blockIdx.y * 64;
  const int lr = lane >> 2, lc8 = (lane & 3) * 8;   // staging coords
  const int l31 = lane & 31, l5 = lane >> 5;        // fragment coords

  f32x16 acc[2];
  acc[0] = (f32x16)0.0f;
  acc[1] = (f32x16)0.0f;

  for (int kt = 0; kt < Ktot; kt += 32) {
    const _Float16 *aH, *aL; int pA, kl;
    if (kt < kcut) { aH = AH0; aL = AL0; pA = ldA0; kl = kt; }
    else           { aH = AH1; aL = AL1; pA = ldA1; kl = kt - kcut; }

    // stage: wave w -> A chunks 2w,2w+1 (hi+lo), B chunk w (hi+lo)
#pragma unroll
    for (int cc = 0; cc < 2; ++cc) {
      const int c = wave * 2 + cc;                  // 16 rows each
      const int arow = mBase + c * 16 + lr;
      gload16(aH + (size_t)arow * pA + kl + lc8, &sAh[c * 512]);
      gload16(aL + (size_t)arow * pA + kl + lc8, &sAl[c * 512]);
    }
    {
      const int brow = nBase + wave * 16 + lr;
      gload16(BH + (size_t)brow * Ktot + kt + lc8, &sBh[wave * 512]);
      gload16(BL + (size_t)brow * Ktot + kt + lc8, &sBl[wave * 512]);
    }
    __syncthreads();

#pragma unroll
    for (int kh = 0; kh < 2; ++kh) {                // two K=16 MFMAs per BK=32
      const int ko = kh * 16 + l5 * 8;
      f16x8 ah[2], al[2], bh, bl;
#pragma unroll
      for (int i = 0; i < 2; ++i) {
        const int off = (wm + i * 32 + l31) * 32 + ko;
        ah[i] = *(const f16x8*)&sAh[off];
        al[i] = *(const f16x8*)&sAl[off];
      }
      {
        const int off = (wn + l31) * 32 + ko;
        bh = *(const f16x8*)&sBh[off];
        bl = *(const f16x8*)&sBl[off];
      }
#pragma unroll
      for (int i = 0; i < 2; ++i) {
        acc[i] = __builtin_amdgcn_mfma_f32_32x32x16_f16(al[i], bh, acc[i], 0, 0, 0);
        acc[i] = __builtin_amdgcn_mfma_f32_32x32x16_f16(ah[i], bl, acc[i], 0, 0, 0);
        acc[i] = __builtin_amdgcn_mfma_f32_32x32x16_f16(ah[i], bh, acc[i], 0, 0, 0);
      }
    }
    __syncthreads();
  }

  const int col = nBase + wn + l31;
  const float bv = bias[col];
#pragma unroll
  for (int i = 0; i < 2; ++i)
#pragma unroll
    for (int r = 0; r < 16; ++r) {
      const int row = mBase + wm + i * 32 + (r & 3) + 8 * (r >> 2) + 4 * l5;
      float v = fmaxf(acc[i][r] + bv, 0.0f);
      const size_t idx = (size_t)row * ldC + col;
      const _Float16 h = (_Float16)v;
      CH[idx] = h;
      CL[idx] = (_Float16)(v - (float)h);
    }
}

// ---- fp16 GEMM (hi-only, 1 MFMA): C = relu(A@B^T + bias) fp16 out,
// or fused-pred mode (sacc != null): sacc[row] += sum_col relu(.)*w3[col]
__global__ __launch_bounds__(256, 4)
void gemm_h_kernel(const _Float16* __restrict__ A0, int ldA0,
                   const _Float16* __restrict__ A1, int ldA1,
                   int kcut, int Ktot,
                   const _Float16* __restrict__ B,
                   const float* __restrict__ bias,
                   _Float16* __restrict__ C, int ldC,
                   const float* __restrict__ w3, float* __restrict__ sacc)
{
  __shared__ _Float16 sAh[128 * 32];
  __shared__ _Float16 sBh[64 * 32];

  const int lane = threadIdx.x & 63;
  const int wave = threadIdx.x >> 6;
  const int wm = (wave >> 1) * 64, wn = (wave & 1) * 32;
  const int mBase = blockIdx.x * 128, nBase = blockIdx.y * 64;
  const int lr = lane >> 2, lc8 = (lane & 3) * 8;
  const int l31 = lane & 31, l5 = lane >> 5;

  f32x16 acc[2];
  acc[0] = (f32x16)0.0f;
  acc[1] = (f32x16)0.0f;

  for (int kt = 0; kt < Ktot; kt += 32) {
    const _Float16* aH; int pA, kl;
    if (kt < kcut) { aH = A0; pA = ldA0; kl = kt; }
    else           { aH = A1; pA = ldA1; kl = kt - kcut; }

#pragma unroll
    for (int cc = 0; cc < 2; ++cc) {
      const int c = wave * 2 + cc;
      const int arow = mBase + c * 16 + lr;
      gload16(aH + (size_t)arow * pA + kl + lc8, &sAh[c * 512]);
    }
    {
      const int brow = nBase + wave * 16 + lr;
      gload16(B + (size_t)brow * Ktot + kt + lc8, &sBh[wave * 512]);
    }
    __syncthreads();

#pragma unroll
    for (int kh = 0; kh < 2; ++kh) {
      const int ko = kh * 16 + l5 * 8;
      f16x8 ah[2], bh;
#pragma unroll
      for (int i = 0; i < 2; ++i)
        ah[i] = *(const f16x8*)&sAh[(wm + i * 32 + l31) * 32 + ko];
      bh = *(const f16x8*)&sBh[(wn + l31) * 32 + ko];
#pragma unroll
      for (int i = 0; i < 2; ++i)
        acc[i] = __builtin_amdgcn_mfma_f32_32x32x16_f16(ah[i], bh, acc[i], 0, 0, 0);
    }
    __syncthreads();
  }

  const int col = nBase + wn + l31;
  const float bv = bias[col];

  if (sacc) {
    const float w3v = w3[col];
#pragma unroll
    for (int i = 0; i < 2; ++i)
#pragma unroll
      for (int r = 0; r < 16; ++r) {
        float pr = fmaxf(acc[i][r] + bv, 0.0f) * w3v;
        pr += __shfl_xor(pr, 1);
        pr += __shfl_xor(pr, 2);
        pr += __shfl_xor(pr, 4);
        pr += __shfl_xor(pr, 8);
        pr += __shfl_xor(pr, 16);
        if (l31 == 0)
          atomicAdd(&sacc[mBase + wm + i * 32 + (r & 3) + 8 * (r >> 2) + 4 * l5], pr);
      }
  } else {
#pragma unroll
    for (int i = 0; i < 2; ++i)
#pragma unroll
      for (int r = 0; r < 16; ++r) {
        const int row = mBase + wm + i * 32 + (r & 3) + 8 * (r >> 2) + 4 * l5;
        float v = fmaxf(acc[i][r] + bv, 0.0f);
        C[(size_t)row * ldC + col] = (_Float16)v;
      }
  }
}

// W (K x N fp32, row-major) -> out (N x K fp16 hi[/lo]), i.e. transposed
__global__ void wconv_kernel(const float* __restrict__ W, int K, int N,
                             _Float16* __restrict__ oH, _Float16* __restrict__ oL) {
  int idx = blockIdx.x * 256 + threadIdx.x;   // idx = n*K + k (output-coalesced)
  if (idx >= K * N) return;
  int n = idx / K, k = idx - n * K;
  float v = W[(size_t)k * N + n];
  _Float16 h = (_Float16)v;
  oH[idx] = h;
  if (oL) oL[idx] = (_Float16)(v - (float)h);
}

__global__ void init_summary_kernel(const float* __restrict__ agg,
                                    _Float16* __restrict__ sH, _Float16* __restrict__ sL,
                                    float* __restrict__ sacc) {
  int idx = blockIdx.x * 256 + threadIdx.x;   // 8192*1024
  float v = agg[idx & 1023];
  _Float16 h = (_Float16)v;
  sH[idx] = h;
  sL[idx] = (_Float16)(v - (float)h);
  if (idx < 8192) sacc[idx] = 0.0f;
}

// towers [n][k][f] fp32 -> towAll [k][n][f] fp16 hi/lo (all 16 slices)
__global__ void tow_conv_all_kernel(const float* __restrict__ towers,
                                    _Float16* __restrict__ oH, _Float16* __restrict__ oL) {
  size_t idx = (size_t)blockIdx.x * 256 + threadIdx.x;  // (k*8192+n)*64+f
  int f = idx & 63;
  int n = (int)((idx >> 6) & 8191);
  int k = (int)(idx >> 19);
  float v = towers[((size_t)n * 16 + k) * 64 + f];
  _Float16 h = (_Float16)v;
  oH[idx] = h;
  oL[idx] = (_Float16)(v - (float)h);
}

// pred = sigmoid(sacc + Ob3); out *= pred; re-zero sacc for next step
__global__ void pred_final_kernel(float* __restrict__ sacc, const float* __restrict__ b3,
                                  float* __restrict__ out, int step) {
  int row = blockIdx.x * 256 + threadIdx.x;   // 8192
  float p = 1.0f / (1.0f + expf(-(sacc[row] + b3[0])));
  out[row] = (step == 0) ? p : out[row] * p;
  sacc[row] = 0.0f;
}

extern "C" void kernel_launch(void* const* d_in, const int* in_sizes, int n_in,
                              void* d_out, int out_size, void* d_ws, size_t ws_size,
                              hipStream_t stream) {
  const float* towers = (const float*)d_in[0];
  const float* agg    = (const float*)d_in[1];
  const float* MW1 = (const float*)d_in[2];
  const float* Mb1 = (const float*)d_in[3];
  const float* MW2 = (const float*)d_in[4];
  const float* Mb2 = (const float*)d_in[5];
  const float* MW3 = (const float*)d_in[6];
  const float* Mb3 = (const float*)d_in[7];
  const float* OW1 = (const float*)d_in[8];
  const float* Ob1 = (const float*)d_in[9];
  const float* OW2 = (const float*)d_in[10];
  const float* Ob2 = (const float*)d_in[11];
  const float* OW3 = (const float*)d_in[12];
  const float* Ob3 = (const float*)d_in[13];
  float* out = (float*)d_out;

  // ws layout (~168 MiB)
  _Float16* p = (_Float16*)d_ws;
  _Float16* MW1tH = p; p += (size_t)1024 * 1088;
  _Float16* MW1tL = p; p += (size_t)1024 * 1088;
  _Float16* OW1tH = p; p += (size_t)1024 * 1088;
  _Float16* MW2tH = p; p += (size_t)1024 * 1024;
  _Float16* MW2tL = p; p += (size_t)1024 * 1024;
  _Float16* OW2tH = p; p += (size_t)1024 * 1024;
  _Float16* MW3tH = p; p += (size_t)1024 * 1024;
  _Float16* MW3tL = p; p += (size_t)1024 * 1024;
  _Float16* sumH  = p; p += (size_t)8192 * 1024;
  _Float16* sumL  = p; p += (size_t)8192 * 1024;
  _Float16* m1H   = p; p += (size_t)8192 * 1024;
  _Float16* m1L   = p; p += (size_t)8192 * 1024;
  _Float16* h1    = p; p += (size_t)8192 * 1024;
  _Float16* m2H   = p; p += (size_t)8192 * 1024;
  _Float16* m2L   = p; p += (size_t)8192 * 1024;
  _Float16* towAllH = p; p += (size_t)16 * 8192 * 64;
  _Float16* towAllL = p; p += (size_t)16 * 8192 * 64;
  float* sacc = (float*)p;

  // per-call setup: transpose+split weights, convert towers, init summary
  {
    int tot = 1088 * 1024;
    wconv_kernel<<<dim3((tot + 255) / 256), dim3(256), 0, stream>>>(MW1, 1088, 1024, MW1tH, MW1tL);
    wconv_kernel<<<dim3((tot + 255) / 256), dim3(256), 0, stream>>>(OW1, 1088, 1024, OW1tH, nullptr);
    tot = 1024 * 1024;
    wconv_kernel<<<dim3((tot + 255) / 256), dim3(256), 0, stream>>>(MW2, 1024, 1024, MW2tH, MW2tL);
    wconv_kernel<<<dim3((tot + 255) / 256), dim3(256), 0, stream>>>(OW2, 1024, 1024, OW2tH, nullptr);
    wconv_kernel<<<dim3((tot + 255) / 256), dim3(256), 0, stream>>>(MW3, 1024, 1024, MW3tH, MW3tL);
    init_summary_kernel<<<dim3(32768), dim3(256), 0, stream>>>(agg, sumH, sumL, sacc);
    tow_conv_all_kernel<<<dim3(32768), dim3(256), 0, stream>>>(towers, towAllH, towAllL);
  }

  const dim3 G(64, 16), B256(256);   // 128x64 tiles over 8192x1024 -> 1024 blocks
  for (int k = 0; k < 16; ++k) {
    const _Float16* towH = towAllH + (size_t)k * 8192 * 64;
    const _Float16* towL = towAllL + (size_t)k * 8192 * 64;

    // K1m: x=[sum|tow] @ MW1^T -> m1 (split)
    gemm_split_kernel<<<G, B256, 0, stream>>>(sumH, sumL, 1024, towH, towL, 64,
                                              1024, 1088, MW1tH, MW1tL, Mb1, m1H, m1L, 1024);
    // K1h: x=[sum|tow] @ OW1^T -> h1 (fp16)
    gemm_h_kernel<<<G, B256, 0, stream>>>(sumH, 1024, towH, 64, 1024, 1088,
                                          OW1tH, Ob1, h1, 1024, nullptr, nullptr);
    // K2m: m1 @ MW2^T -> m2 (split)
    gemm_split_kernel<<<G, B256, 0, stream>>>(m1H, m1L, 1024, m1H, m1L, 1024,
                                              1024, 1024, MW2tH, MW2tL, Mb2, m2H, m2L, 1024);
    // K2h: h1 @ OW2^T -> fused relu+dot(OW3) into sacc (fp16)
    gemm_h_kernel<<<G, B256, 0, stream>>>(h1, 1024, h1, 1024, 1024, 1024,
                                          OW2tH, Ob2, nullptr, 1024, OW3, sacc);
    // K3: m2 @ MW3^T -> summary (split, in-place: K1m/K1h already consumed it)
    gemm_split_kernel<<<G, B256, 0, stream>>>(m2H, m2L, 1024, m2H, m2L, 1024,
                                              1024, 1024, MW3tH, MW3tL, Mb3, sumH, sumL, 1024);
    // pred + product accumulate + re-zero sacc
    pred_final_kernel<<<dim3(32), B256, 0, stream>>>(sacc, Ob3, out, k);
  }
}

// Round 6
// 3641.237 us; speedup vs baseline: 1.3202x; 1.3202x over previous
//
#include <hip/hip_runtime.h>
#include <cstdint>
#include <cstddef>

// BottomUpNet: N=8192 rows independent; K=16 sequential steps.
// m-chain (summary recurrence): fp16 hi/lo split, 3 MFMAs => ~fp32 exact.
// h-chain (h1,h2 -> pred): plain fp16, 1 MFMA (non-compounding).
// R6: R4 structure (128x128 tile, 32x32x16 MFMA) + XOR-swizzled LDS K-segment
// layout. R4/R5 rocprof showed 30-40% of GEMM cycles were LDS bank-conflict
// serialization (frag-read row stride 64B = 16 banks -> 8/32 banks active).
// LDS slot (row,c) holds global seg c ^ (row&3) ^ ((row>>2)&3): staging
// permutes each lane's global source seg (stays in-row, coalesced);
// frag reads XOR the seg index. Uniform 32-bank load -> 8-cyc b128 minimum.

typedef _Float16 f16x8 __attribute__((ext_vector_type(8)));
typedef float f32x16 __attribute__((ext_vector_type(16)));

__device__ __forceinline__ void gload16(const void* g, void* l) {
  // async global->LDS, 16B/lane, LDS dest = wave-uniform base + lane*16
  __builtin_amdgcn_global_load_lds(
      (__attribute__((address_space(1))) void*)const_cast<void*>(g),
      (__attribute__((address_space(3))) void*)l,
      16, 0, 0);
}

// ---- split GEMM: C = relu(A@B^T + bias), A,B,C hi/lo fp16 (3 MFMAs => ~fp32)
// Tile 128x128, BK=32, 256 thr (4 waves, each 64x64 = 2x2 of 32x32 MFMA tiles).
__global__ __launch_bounds__(256, 3)
void gemm_split_kernel(const _Float16* __restrict__ AH0, const _Float16* __restrict__ AL0, int ldA0,
                       const _Float16* __restrict__ AH1, const _Float16* __restrict__ AL1, int ldA1,
                       int kcut, int Ktot,
                       const _Float16* __restrict__ BH, const _Float16* __restrict__ BL,
                       const float* __restrict__ bias,
                       _Float16* __restrict__ CH, _Float16* __restrict__ CL, int ldC)
{
  __shared__ _Float16 sAh[128 * 32];
  __shared__ _Float16 sAl[128 * 32];
  __shared__ _Float16 sBh[128 * 32];
  __shared__ _Float16 sBl[128 * 32];

  const int lane = threadIdx.x & 63;
  const int wave = threadIdx.x >> 6;
  const int wm = (wave >> 1) * 64, wn = (wave & 1) * 64;
  const int mBase = blockIdx.x * 128, nBase = blockIdx.y * 128;

  // staging coords: 16 rows/chunk, 4 lanes/row; swizzled global seg per lane
  const int lr = lane >> 2;
  const int lcs8 = (((lane & 3) ^ (lr & 3) ^ ((lr >> 2) & 3)) * 8);

  // fragment coords + read-side swizzle
  const int l31 = lane & 31, l5 = lane >> 5;
  const int fswz = (l31 & 3) ^ ((l31 >> 2) & 3);

  f32x16 acc[2][2];
#pragma unroll
  for (int i = 0; i < 2; ++i)
#pragma unroll
    for (int j = 0; j < 2; ++j)
      acc[i][j] = (f32x16)0.0f;

  for (int kt = 0; kt < Ktot; kt += 32) {
    const _Float16 *aH, *aL; int pA, kl;
    if (kt < kcut) { aH = AH0; aL = AL0; pA = ldA0; kl = kt; }
    else           { aH = AH1; aL = AL1; pA = ldA1; kl = kt - kcut; }

#pragma unroll
    for (int cc = 0; cc < 2; ++cc) {
      const int c = wave * 2 + cc;                  // chunk 0..7, 16 rows each
      const int arow = mBase + c * 16 + lr;
      const int brow = nBase + c * 16 + lr;
      gload16(aH + (size_t)arow * pA   + kl + lcs8, &sAh[c * 512]);
      gload16(aL + (size_t)arow * pA   + kl + lcs8, &sAl[c * 512]);
      gload16(BH + (size_t)brow * Ktot + kt + lcs8, &sBh[c * 512]);
      gload16(BL + (size_t)brow * Ktot + kt + lcs8, &sBl[c * 512]);
    }
    __syncthreads();

#pragma unroll
    for (int kh = 0; kh < 2; ++kh) {                // two K=16 MFMAs per BK=32
      const int ko = ((kh * 2 + l5) ^ fswz) * 8;    // swizzled seg
      f16x8 ah[2], al[2], bh[2], bl[2];
#pragma unroll
      for (int i = 0; i < 2; ++i) {
        const int off = (wm + i * 32 + l31) * 32 + ko;
        ah[i] = *(const f16x8*)&sAh[off];
        al[i] = *(const f16x8*)&sAl[off];
      }
#pragma unroll
      for (int j = 0; j < 2; ++j) {
        const int off = (wn + j * 32 + l31) * 32 + ko;
        bh[j] = *(const f16x8*)&sBh[off];
        bl[j] = *(const f16x8*)&sBl[off];
      }
#pragma unroll
      for (int i = 0; i < 2; ++i)
#pragma unroll
        for (int j = 0; j < 2; ++j) {
          acc[i][j] = __builtin_amdgcn_mfma_f32_32x32x16_f16(al[i], bh[j], acc[i][j], 0, 0, 0);
          acc[i][j] = __builtin_amdgcn_mfma_f32_32x32x16_f16(ah[i], bl[j], acc[i][j], 0, 0, 0);
          acc[i][j] = __builtin_amdgcn_mfma_f32_32x32x16_f16(ah[i], bh[j], acc[i][j], 0, 0, 0);
        }
    }
    __syncthreads();
  }

  float bv[2];
#pragma unroll
  for (int j = 0; j < 2; ++j) bv[j] = bias[nBase + wn + j * 32 + l31];
#pragma unroll
  for (int i = 0; i < 2; ++i)
#pragma unroll
    for (int j = 0; j < 2; ++j)
#pragma unroll
      for (int r = 0; r < 16; ++r) {
        const int row = mBase + wm + i * 32 + (r & 3) + 8 * (r >> 2) + 4 * l5;
        const int col = nBase + wn + j * 32 + l31;
        float v = fmaxf(acc[i][j][r] + bv[j], 0.0f);
        const size_t idx = (size_t)row * ldC + col;
        const _Float16 h = (_Float16)v;
        CH[idx] = h;
        CL[idx] = (_Float16)(v - (float)h);
      }
}

// ---- fp16 GEMM (hi-only, 1 MFMA): C = relu(A@B^T + bias) fp16 out,
// or fused-pred mode (sacc != null): sacc[row] += sum_col relu(.)*w3[col]
__global__ __launch_bounds__(256, 3)
void gemm_h_kernel(const _Float16* __restrict__ A0, int ldA0,
                   const _Float16* __restrict__ A1, int ldA1,
                   int kcut, int Ktot,
                   const _Float16* __restrict__ B,
                   const float* __restrict__ bias,
                   _Float16* __restrict__ C, int ldC,
                   const float* __restrict__ w3, float* __restrict__ sacc)
{
  __shared__ _Float16 sAh[128 * 32];
  __shared__ _Float16 sBh[128 * 32];

  const int lane = threadIdx.x & 63;
  const int wave = threadIdx.x >> 6;
  const int wm = (wave >> 1) * 64, wn = (wave & 1) * 64;
  const int mBase = blockIdx.x * 128, nBase = blockIdx.y * 128;

  const int lr = lane >> 2;
  const int lcs8 = (((lane & 3) ^ (lr & 3) ^ ((lr >> 2) & 3)) * 8);
  const int l31 = lane & 31, l5 = lane >> 5;
  const int fswz = (l31 & 3) ^ ((l31 >> 2) & 3);

  f32x16 acc[2][2];
#pragma unroll
  for (int i = 0; i < 2; ++i)
#pragma unroll
    for (int j = 0; j < 2; ++j)
      acc[i][j] = (f32x16)0.0f;

  for (int kt = 0; kt < Ktot; kt += 32) {
    const _Float16* aH; int pA, kl;
    if (kt < kcut) { aH = A0; pA = ldA0; kl = kt; }
    else           { aH = A1; pA = ldA1; kl = kt - kcut; }

#pragma unroll
    for (int cc = 0; cc < 2; ++cc) {
      const int c = wave * 2 + cc;
      const int arow = mBase + c * 16 + lr;
      const int brow = nBase + c * 16 + lr;
      gload16(aH + (size_t)arow * pA   + kl + lcs8, &sAh[c * 512]);
      gload16(B  + (size_t)brow * Ktot + kt + lcs8, &sBh[c * 512]);
    }
    __syncthreads();

#pragma unroll
    for (int kh = 0; kh < 2; ++kh) {
      const int ko = ((kh * 2 + l5) ^ fswz) * 8;
      f16x8 ah[2], bh[2];
#pragma unroll
      for (int i = 0; i < 2; ++i)
        ah[i] = *(const f16x8*)&sAh[(wm + i * 32 + l31) * 32 + ko];
#pragma unroll
      for (int j = 0; j < 2; ++j)
        bh[j] = *(const f16x8*)&sBh[(wn + j * 32 + l31) * 32 + ko];
#pragma unroll
      for (int i = 0; i < 2; ++i)
#pragma unroll
        for (int j = 0; j < 2; ++j)
          acc[i][j] = __builtin_amdgcn_mfma_f32_32x32x16_f16(ah[i], bh[j], acc[i][j], 0, 0, 0);
    }
    __syncthreads();
  }

  float bv[2], w3v[2];
#pragma unroll
  for (int j = 0; j < 2; ++j) {
    const int col = nBase + wn + j * 32 + l31;
    bv[j] = bias[col];
    w3v[j] = sacc ? w3[col] : 0.0f;
  }

  if (sacc) {
    // fused pred partial: one value per C/D row, reduced over the 32 col-lanes
#pragma unroll
    for (int i = 0; i < 2; ++i)
#pragma unroll
      for (int r = 0; r < 16; ++r) {
        float pr = 0.0f;
#pragma unroll
        for (int j = 0; j < 2; ++j)
          pr += fmaxf(acc[i][j][r] + bv[j], 0.0f) * w3v[j];
        pr += __shfl_xor(pr, 1);
        pr += __shfl_xor(pr, 2);
        pr += __shfl_xor(pr, 4);
        pr += __shfl_xor(pr, 8);
        pr += __shfl_xor(pr, 16);
        if (l31 == 0)
          atomicAdd(&sacc[mBase + wm + i * 32 + (r & 3) + 8 * (r >> 2) + 4 * l5], pr);
      }
  } else {
#pragma unroll
    for (int i = 0; i < 2; ++i)
#pragma unroll
      for (int j = 0; j < 2; ++j)
#pragma unroll
        for (int r = 0; r < 16; ++r) {
          const int row = mBase + wm + i * 32 + (r & 3) + 8 * (r >> 2) + 4 * l5;
          const int col = nBase + wn + j * 32 + l31;
          float v = fmaxf(acc[i][j][r] + bv[j], 0.0f);
          C[(size_t)row * ldC + col] = (_Float16)v;
        }
  }
}

// W (K x N fp32, row-major) -> out (N x K fp16 hi[/lo]), i.e. transposed
__global__ void wconv_kernel(const float* __restrict__ W, int K, int N,
                             _Float16* __restrict__ oH, _Float16* __restrict__ oL) {
  int idx = blockIdx.x * 256 + threadIdx.x;   // idx = n*K + k (output-coalesced)
  if (idx >= K * N) return;
  int n = idx / K, k = idx - n * K;
  float v = W[(size_t)k * N + n];
  _Float16 h = (_Float16)v;
  oH[idx] = h;
  if (oL) oL[idx] = (_Float16)(v - (float)h);
}

__global__ void init_summary_kernel(const float* __restrict__ agg,
                                    _Float16* __restrict__ sH, _Float16* __restrict__ sL,
                                    float* __restrict__ sacc) {
  int idx = blockIdx.x * 256 + threadIdx.x;   // 8192*1024
  float v = agg[idx & 1023];
  _Float16 h = (_Float16)v;
  sH[idx] = h;
  sL[idx] = (_Float16)(v - (float)h);
  if (idx < 8192) sacc[idx] = 0.0f;
}

// towers [n][k][f] fp32 -> towAll [k][n][f] fp16 hi/lo (all 16 slices)
__global__ void tow_conv_all_kernel(const float* __restrict__ towers,
                                    _Float16* __restrict__ oH, _Float16* __restrict__ oL) {
  size_t idx = (size_t)blockIdx.x * 256 + threadIdx.x;  // (k*8192+n)*64+f
  int f = idx & 63;
  int n = (int)((idx >> 6) & 8191);
  int k = (int)(idx >> 19);
  float v = towers[((size_t)n * 16 + k) * 64 + f];
  _Float16 h = (_Float16)v;
  oH[idx] = h;
  oL[idx] = (_Float16)(v - (float)h);
}

// pred = sigmoid(sacc + Ob3); out *= pred; re-zero sacc for next step
__global__ void pred_final_kernel(float* __restrict__ sacc, const float* __restrict__ b3,
                                  float* __restrict__ out, int step) {
  int row = blockIdx.x * 256 + threadIdx.x;   // 8192
  float p = 1.0f / (1.0f + expf(-(sacc[row] + b3[0])));
  out[row] = (step == 0) ? p : out[row] * p;
  sacc[row] = 0.0f;
}

extern "C" void kernel_launch(void* const* d_in, const int* in_sizes, int n_in,
                              void* d_out, int out_size, void* d_ws, size_t ws_size,
                              hipStream_t stream) {
  const float* towers = (const float*)d_in[0];
  const float* agg    = (const float*)d_in[1];
  const float* MW1 = (const float*)d_in[2];
  const float* Mb1 = (const float*)d_in[3];
  const float* MW2 = (const float*)d_in[4];
  const float* Mb2 = (const float*)d_in[5];
  const float* MW3 = (const float*)d_in[6];
  const float* Mb3 = (const float*)d_in[7];
  const float* OW1 = (const float*)d_in[8];
  const float* Ob1 = (const float*)d_in[9];
  const float* OW2 = (const float*)d_in[10];
  const float* Ob2 = (const float*)d_in[11];
  const float* OW3 = (const float*)d_in[12];
  const float* Ob3 = (const float*)d_in[13];
  float* out = (float*)d_out;

  // ws layout (~168 MiB)
  _Float16* p = (_Float16*)d_ws;
  _Float16* MW1tH = p; p += (size_t)1024 * 1088;
  _Float16* MW1tL = p; p += (size_t)1024 * 1088;
  _Float16* OW1tH = p; p += (size_t)1024 * 1088;
  _Float16* MW2tH = p; p += (size_t)1024 * 1024;
  _Float16* MW2tL = p; p += (size_t)1024 * 1024;
  _Float16* OW2tH = p; p += (size_t)1024 * 1024;
  _Float16* MW3tH = p; p += (size_t)1024 * 1024;
  _Float16* MW3tL = p; p += (size_t)1024 * 1024;
  _Float16* sumH  = p; p += (size_t)8192 * 1024;
  _Float16* sumL  = p; p += (size_t)8192 * 1024;
  _Float16* m1H   = p; p += (size_t)8192 * 1024;
  _Float16* m1L   = p; p += (size_t)8192 * 1024;
  _Float16* h1    = p; p += (size_t)8192 * 1024;
  _Float16* m2H   = p; p += (size_t)8192 * 1024;
  _Float16* m2L   = p; p += (size_t)8192 * 1024;
  _Float16* towAllH = p; p += (size_t)16 * 8192 * 64;
  _Float16* towAllL = p; p += (size_t)16 * 8192 * 64;
  float* sacc = (float*)p;

  // per-call setup: transpose+split weights, convert towers, init summary
  {
    int tot = 1088 * 1024;
    wconv_kernel<<<dim3((tot + 255) / 256), dim3(256), 0, stream>>>(MW1, 1088, 1024, MW1tH, MW1tL);
    wconv_kernel<<<dim3((tot + 255) / 256), dim3(256), 0, stream>>>(OW1, 1088, 1024, OW1tH, nullptr);
    tot = 1024 * 1024;
    wconv_kernel<<<dim3((tot + 255) / 256), dim3(256), 0, stream>>>(MW2, 1024, 1024, MW2tH, MW2tL);
    wconv_kernel<<<dim3((tot + 255) / 256), dim3(256), 0, stream>>>(OW2, 1024, 1024, OW2tH, nullptr);
    wconv_kernel<<<dim3((tot + 255) / 256), dim3(256), 0, stream>>>(MW3, 1024, 1024, MW3tH, MW3tL);
    init_summary_kernel<<<dim3(32768), dim3(256), 0, stream>>>(agg, sumH, sumL, sacc);
    tow_conv_all_kernel<<<dim3(32768), dim3(256), 0, stream>>>(towers, towAllH, towAllL);
  }

  const dim3 G(64, 8), B256(256);   // 128x128 tiles over 8192x1024 -> 512 blocks
  for (int k = 0; k < 16; ++k) {
    const _Float16* towH = towAllH + (size_t)k * 8192 * 64;
    const _Float16* towL = towAllL + (size_t)k * 8192 * 64;

    // K1m: x=[sum|tow] @ MW1^T -> m1 (split)
    gemm_split_kernel<<<G, B256, 0, stream>>>(sumH, sumL, 1024, towH, towL, 64,
                                              1024, 1088, MW1tH, MW1tL, Mb1, m1H, m1L, 1024);
    // K1h: x=[sum|tow] @ OW1^T -> h1 (fp16)
    gemm_h_kernel<<<G, B256, 0, stream>>>(sumH, 1024, towH, 64, 1024, 1088,
                                          OW1tH, Ob1, h1, 1024, nullptr, nullptr);
    // K2m: m1 @ MW2^T -> m2 (split)
    gemm_split_kernel<<<G, B256, 0, stream>>>(m1H, m1L, 1024, m1H, m1L, 1024,
                                              1024, 1024, MW2tH, MW2tL, Mb2, m2H, m2L, 1024);
    // K2h: h1 @ OW2^T -> fused relu+dot(OW3) into sacc (fp16)
    gemm_h_kernel<<<G, B256, 0, stream>>>(h1, 1024, h1, 1024, 1024, 1024,
                                          OW2tH, Ob2, nullptr, 1024, OW3, sacc);
    // K3: m2 @ MW3^T -> summary (split, in-place: K1m/K1h already consumed it)
    gemm_split_kernel<<<G, B256, 0, stream>>>(m2H, m2L, 1024, m2H, m2L, 1024,
                                              1024, 1024, MW3tH, MW3tL, Mb3, sumH, sumL, 1024);
    // pred + product accumulate + re-zero sacc
    pred_final_kernel<<<dim3(32), B256, 0, stream>>>(sacc, Ob3, out, k);
  }
}